// Round 13
// baseline (326.026 us; speedup 1.0000x reference)
//
#include <hip/hip_runtime.h>
#include <math.h>

// Problem constants (from reference)
#define BG    100        // graphs
#define NPG   500        // nodes per graph (layer 1)
#define FD    128        // feature dim (F_IN == H == 128)
#define EE    600000     // edges
#define EPG   6000       // edges per graph (contiguous, never cross graphs)
#define NN    50000      // total nodes layer 1
#define K1    250
#define K2    125
#define K3    63
#define CAP   64         // max in-degree capacity (in-deg ~ Poisson(12); P(>64) ~ 1e-30)

// XCD-aligned swizzle: physical block p (round-robin over 8 XCDs via p%8) ->
// work item such that contiguous work fractions land on one XCD. Bijective.
__device__ __forceinline__ int swz(int p, int N) {
    int j = p & 7, i = p >> 3;
    int chunk = N >> 3, rem = N & 7;
    int mj = j < rem ? j : rem;
    return j * chunk + mj + i;
}

// ---------------- layer-1 CSR build: one block per graph, LDS counters ----------------
__global__ __launch_bounds__(1024) void fill_first_kernel(const int* __restrict__ ei,
                                                          int* __restrict__ deg,
                                                          int* __restrict__ col) {
    __shared__ int lcnt[NPG];
    int b = swz(blockIdx.x, BG), tid = threadIdx.x;
    for (int i = tid; i < NPG; i += 1024) lcnt[i] = 0;
    __syncthreads();
    for (int e0 = tid; e0 < EPG; e0 += 1024) {
        int e = b * EPG + e0;
        int d = ei[EE + e];
        int pos = atomicAdd(&lcnt[d - b * NPG], 1);
        if (pos < CAP) col[(long long)d * CAP + pos] = ei[e];
    }
    __syncthreads();
    for (int i = tid; i < NPG; i += 1024) deg[b * NPG + i] = lcnt[i];
}

// ---------------- gather-aggregate: mean of neighbor rows ----------------
// 32 lanes per node (float4), 2 nodes per wave. 4-way software-pipelined
// neighbor loop (R12 win: independent loads batched, adds in original order).
// Do NOT fuse into the GEMM (R6: 5x FETCH) or register-prefetch there (R8).
__global__ void gather_agg_kernel(const int* __restrict__ deg, const int* __restrict__ col,
                                  const float* __restrict__ x, float* __restrict__ mean,
                                  int n, int NB) {
    int g = swz(blockIdx.x, NB) * 256 + threadIdx.x;
    int node = g >> 5, sub = g & 31;
    if (node >= n) return;
    int d = deg[node]; if (d > CAP) d = CAP;
    const int* cp = col + (long long)node * CAP;
    float ax = 0.0f, ay = 0.0f, az = 0.0f, aw = 0.0f;
    int j = 0;
    for (; j + 4 <= d; j += 4) {
        int s0 = cp[j], s1 = cp[j + 1], s2 = cp[j + 2], s3 = cp[j + 3];
        float4 v0 = ((const float4*)(x + (long long)s0 * FD))[sub];
        float4 v1 = ((const float4*)(x + (long long)s1 * FD))[sub];
        float4 v2 = ((const float4*)(x + (long long)s2 * FD))[sub];
        float4 v3 = ((const float4*)(x + (long long)s3 * FD))[sub];
        ax += v0.x; ay += v0.y; az += v0.z; aw += v0.w;
        ax += v1.x; ay += v1.y; az += v1.z; aw += v1.w;
        ax += v2.x; ay += v2.y; az += v2.z; aw += v2.w;
        ax += v3.x; ay += v3.y; az += v3.z; aw += v3.w;
    }
    for (; j < d; ++j) {
        float4 v = ((const float4*)(x + (long long)cp[j] * FD))[sub];
        ax += v.x; ay += v.y; az += v.z; aw += v.w;
    }
    float inv = 1.0f / fmaxf((float)d, 1.0f);
    float4 o; o.x = ax * inv; o.y = ay * inv; o.z = az * inv; o.w = aw * inv;
    ((float4*)(mean + (long long)node * FD))[sub] = o;
}

// ---------------- fused SAGE GEMM + score epilogue ----------------
// h = relu(mean@Wl + x@Wr + bl); score = tanh(h.pw / ||pw||)
// Templated tile rows: ROWS=64 for L1 (3.05 blk/CU, the pinned-58us proven
// shape), ROWS=32 for L2/L3 to fix block-granularity imbalance (R7 lesson:
// 1.5 blk/CU wastes half the machine in a second round).
template<int ROWS>
__global__ __launch_bounds__(256) void sage_gemm_kernel(
        const float* __restrict__ mean, const float* __restrict__ x,
        const float* __restrict__ Wl, const float* __restrict__ Wr,
        const float* __restrict__ bl, const float* __restrict__ pw,
        float* __restrict__ hout, float* __restrict__ score, int M, int NB) {
    constexpr int STR = ROWS + 4;    // As stride
    constexpr int RPT = ROWS / 16;   // rows per thread (4 or 2)
    __shared__ __align__(16) float As[32 * STR];
    __shared__ __align__(16) float Ws[32 * 128];
    __shared__ float spart[ROWS * 16];
    __shared__ float snrmp[16];
    int tid  = threadIdx.x;
    int row0 = swz(blockIdx.x, NB) * ROWS;
    int tr   = tid >> 4;             // 0..15 -> rows RPT*tr..
    int tc   = tid & 15;             // 0..15 -> cols {4tc.., 64+4tc..}
    float acc[RPT][8];
#pragma unroll
    for (int r = 0; r < RPT; r++)
#pragma unroll
        for (int c = 0; c < 8; c++) acc[r][c] = 0.0f;

    int lrow = tid >> 3;             // 0..31
    int lk   = (tid & 7) * 4;        // 0,4,..,28

    for (int kt = 0; kt < 8; ++kt) {
        bool isMean = kt < 4;
        int kcol = (isMean ? kt * 32 : (kt - 4) * 32) + lk;
        const float* Ab = isMean ? mean : x;
#pragma unroll
        for (int p = 0; p < ROWS / 32; ++p) {
            int row  = p * 32 + lrow;
            int grow = row0 + row; if (grow > M - 1) grow = M - 1;
            float4 v = *(const float4*)(Ab + (long long)grow * FD + kcol);
            As[(lk + 0) * STR + row] = v.x;
            As[(lk + 1) * STR + row] = v.y;
            As[(lk + 2) * STR + row] = v.z;
            As[(lk + 3) * STR + row] = v.w;
        }
        {
            int wc  = (tid & 31) * 4;
            int wk0 = tid >> 5;
            const float* WB = isMean ? Wl : Wr;
            int krow0 = (isMean ? kt : kt - 4) * 32;
#pragma unroll
            for (int q = 0; q < 4; ++q) {
                int kk = wk0 + q * 8;
                *(float4*)&Ws[kk * 128 + wc] = *(const float4*)(WB + (long long)(krow0 + kk) * FD + wc);
            }
        }
        __syncthreads();
#pragma unroll
        for (int kk = 0; kk < 32; ++kk) {
            float av[RPT];
            if constexpr (RPT == 4) {
                float4 a = *(const float4*)&As[kk * STR + tr * 4];
                av[0] = a.x; av[1] = a.y; av[2] = a.z; av[3] = a.w;
            } else {
                float2 a = *(const float2*)&As[kk * STR + tr * 2];
                av[0] = a.x; av[1] = a.y;
            }
            float4 b0 = *(const float4*)&Ws[kk * 128 + tc * 4];
            float4 b1 = *(const float4*)&Ws[kk * 128 + 64 + tc * 4];
            float bv[8] = {b0.x, b0.y, b0.z, b0.w, b1.x, b1.y, b1.z, b1.w};
#pragma unroll
            for (int r = 0; r < RPT; r++)
#pragma unroll
                for (int c = 0; c < 8; c++) acc[r][c] += av[r] * bv[c];
        }
        __syncthreads();
    }

    float4 bb0 = *(const float4*)(bl + tc * 4);
    float4 bb1 = *(const float4*)(bl + 64 + tc * 4);
    float4 w0  = *(const float4*)(pw + tc * 4);
    float4 w1  = *(const float4*)(pw + 64 + tc * 4);
    float bvec[8] = {bb0.x, bb0.y, bb0.z, bb0.w, bb1.x, bb1.y, bb1.z, bb1.w};
    float wvec[8] = {w0.x, w0.y, w0.z, w0.w, w1.x, w1.y, w1.z, w1.w};
    if (tr == 0) snrmp[tc] = w0.x*w0.x + w0.y*w0.y + w0.z*w0.z + w0.w*w0.w +
                             w1.x*w1.x + w1.y*w1.y + w1.z*w1.z + w1.w*w1.w;
#pragma unroll
    for (int r = 0; r < RPT; r++) {
        int row  = tr * RPT + r;
        int grow = row0 + row;
        float h[8];
        float part = 0.0f;
#pragma unroll
        for (int c = 0; c < 8; c++) {
            h[c] = fmaxf(acc[r][c] + bvec[c], 0.0f);
            part += h[c] * wvec[c];
        }
        spart[row * 16 + tc] = part;
        if (grow < M) {
            float* dstp = hout + (long long)grow * FD;
            *(float4*)(dstp + tc * 4)      = make_float4(h[0], h[1], h[2], h[3]);
            *(float4*)(dstp + 64 + tc * 4) = make_float4(h[4], h[5], h[6], h[7]);
        }
    }
    __syncthreads();
    if (tid < ROWS) {
        int grow = row0 + tid;
        if (grow < M) {
            float dot = 0.0f;
#pragma unroll
            for (int i = 0; i < 16; i++) dot += spart[tid * 16 + i];
            float nr = 0.0f;
#pragma unroll
            for (int i = 0; i < 16; i++) nr += snrmp[i];
            score[grow] = tanhf(dot / sqrtf(nr));
        }
    }
}

// ---------------- fused per-graph tail: top-k sort + LDS mapping + edge remap +
// next-layer CSR fill + gather*score + readout (+ MLP head on last layer) --------
// One block per graph, 1024 threads. mode: 0 = z=, 1 = z+=, 2 = z-final + head.
__global__ __launch_bounds__(1024) void topk_tail_kernel(
        const float* __restrict__ score, const float* __restrict__ hout,
        int n_per, int k, int SN,
        float* __restrict__ xp,
        const int* __restrict__ esrc, const int* __restrict__ edst,
        const float* __restrict__ em_in,
        int* __restrict__ src_out, int* __restrict__ dst_out, float* __restrict__ em_out,
        int* __restrict__ next_deg, int* __restrict__ next_col,
        float* __restrict__ z, int mode,
        const float* __restrict__ W1, const float* __restrict__ b1,
        const float* __restrict__ W2, const float* __restrict__ b2,
        const float* __restrict__ W3, const float* __restrict__ b3,
        float* __restrict__ out) {
    __shared__ float skey[512];
    __shared__ int   sidx[512];
    __shared__ int   lmap[512];
    __shared__ int   lcnt[512];
    __shared__ float pmax[1024];
    __shared__ float psum[1024];
    __shared__ float zs[256], t1[128], t2[64], t3[16];
    int b = swz(blockIdx.x, BG), tid = threadIdx.x;

    for (int i = tid; i < SN; i += 1024) {
        if (i < n_per) { skey[i] = score[b * n_per + i]; sidx[i] = i; }
        else           { skey[i] = -INFINITY;            sidx[i] = 0x7fffffff; }
        lmap[i] = -1;
        lcnt[i] = 0;
    }
    __syncthreads();

    // bitonic sort: desc value, tie -> asc index (jax.lax.top_k order)
    for (int ks = 2; ks <= SN; ks <<= 1) {
        for (int j = ks >> 1; j > 0; j >>= 1) {
            for (int i = tid; i < SN; i += 1024) {
                int l = i ^ j;
                if (l > i) {
                    float ki = skey[i], kl = skey[l];
                    int   ii = sidx[i], il = sidx[l];
                    bool before = (ki > kl) || (ki == kl && ii < il);
                    bool up = ((i & ks) == 0);
                    if (up ? !before : before) {
                        skey[i] = kl; skey[l] = ki;
                        sidx[i] = il; sidx[l] = ii;
                    }
                }
            }
            __syncthreads();
        }
    }

    // local old->new mapping for kept nodes
    for (int i = tid; i < k; i += 1024) lmap[sidx[i]] = i;
    __syncthreads();

    // edge phase: remap this graph's edges; slot-fill next layer's CSR
    if (esrc) {
        int nbase = b * n_per, kbase = b * k;
        for (int e0 = tid; e0 < EPG; e0 += 1024) {
            int e = b * EPG + e0;
            bool alive = em_in ? (em_in[e] != 0.0f) : true;
            if (alive) {
                int ls = lmap[esrc[e] - nbase];
                int ld = lmap[edst[e] - nbase];
                bool keep = (ls >= 0) && (ld >= 0);
                if (keep) {
                    int pos = atomicAdd(&lcnt[ld], 1);
                    if (pos < CAP) next_col[(long long)(kbase + ld) * CAP + pos] = kbase + ls;
                }
                if (em_out) {
                    em_out[e]  = keep ? 1.0f : 0.0f;
                    src_out[e] = keep ? kbase + ls : 0;
                    dst_out[e] = keep ? kbase + ld : 0;
                }
            } else if (em_out) {
                em_out[e] = 0.0f; src_out[e] = 0; dst_out[e] = 0;
            }
        }
        __syncthreads();
        for (int i = tid; i < k; i += 1024) next_deg[b * k + i] = lcnt[i];
    }

    // gather + scale + readout partials: c = channel, s = row slice (8 slices),
    // 4-way unrolled (R12 win: independent hout loads batched, order-preserving adds)
    int c = tid & 127, s = tid >> 7;
    float mx = -INFINITY, sm = 0.0f;
    {
        int r = s;
        long long hbase = (long long)b * n_per * FD + c;
        long long xbase = (long long)b * k * FD + c;
        for (; r + 24 < k; r += 32) {
            int i0 = sidx[r], i1 = sidx[r + 8], i2 = sidx[r + 16], i3 = sidx[r + 24];
            float k0 = skey[r], k1 = skey[r + 8], k2 = skey[r + 16], k3 = skey[r + 24];
            float v0 = hout[hbase + (long long)i0 * FD] * k0;
            float v1 = hout[hbase + (long long)i1 * FD] * k1;
            float v2 = hout[hbase + (long long)i2 * FD] * k2;
            float v3 = hout[hbase + (long long)i3 * FD] * k3;
            xp[xbase + (long long)(r)      * FD] = v0;
            xp[xbase + (long long)(r + 8)  * FD] = v1;
            xp[xbase + (long long)(r + 16) * FD] = v2;
            xp[xbase + (long long)(r + 24) * FD] = v3;
            mx = fmaxf(mx, v0); sm += v0;
            mx = fmaxf(mx, v1); sm += v1;
            mx = fmaxf(mx, v2); sm += v2;
            mx = fmaxf(mx, v3); sm += v3;
        }
        for (; r < k; r += 8) {
            float v = hout[hbase + (long long)sidx[r] * FD] * skey[r];
            xp[xbase + (long long)r * FD] = v;
            mx = fmaxf(mx, v); sm += v;
        }
    }
    pmax[tid] = mx; psum[tid] = sm;
    __syncthreads();
    if (tid < 128) {
        float m = -INFINITY, su = 0.0f;
#pragma unroll
        for (int i = 0; i < 8; i++) {
            m = fmaxf(m, pmax[i * 128 + tid]);
            su += psum[i * 128 + tid];
        }
        float mean = su / (float)k;
        if (mode == 0)      { z[b * 256 + tid] = m;  z[b * 256 + 128 + tid] = mean;  }
        else if (mode == 1) { z[b * 256 + tid] += m; z[b * 256 + 128 + tid] += mean; }
        else {
            zs[tid]       = z[b * 256 + tid] + m;
            zs[128 + tid] = z[b * 256 + 128 + tid] + mean;
        }
    }
    if (mode == 2) {
        __syncthreads();
        if (tid < 128) {
            float a = b1[tid];
            for (int kk = 0; kk < 256; kk++) a += zs[kk] * W1[kk * 128 + tid];
            t1[tid] = fmaxf(a, 0.0f);
        }
        __syncthreads();
        if (tid < 64) {
            float a = b2[tid];
            for (int kk = 0; kk < 128; kk++) a += t1[kk] * W2[kk * 64 + tid];
            t2[tid] = fmaxf(a, 0.0f);
        }
        __syncthreads();
        if (tid < 10) {
            float a = b3[tid];
            for (int kk = 0; kk < 64; kk++) a += t2[kk] * W3[kk * 10 + tid];
            t3[tid] = a;
        }
        __syncthreads();
        if (tid == 0) {
            float m = -INFINITY;
            for (int i = 0; i < 10; i++) m = fmaxf(m, t3[i]);
            float su = 0.0f;
            for (int i = 0; i < 10; i++) su += expf(t3[i] - m);
            float ls = logf(su);
            for (int i = 0; i < 10; i++) out[b * 10 + i] = t3[i] - m - ls;
        }
    }
}

extern "C" void kernel_launch(void* const* d_in, const int* in_sizes, int n_in,
                              void* d_out, int out_size, void* d_ws, size_t ws_size,
                              hipStream_t stream) {
    (void)in_sizes; (void)n_in; (void)out_size; (void)ws_size;
    const float* x   = (const float*)d_in[0];
    const int*   ei  = (const int*)d_in[1];
    const float* Wl1 = (const float*)d_in[2];
    const float* bl1 = (const float*)d_in[3];
    const float* Wr1 = (const float*)d_in[4];
    const float* Wl2 = (const float*)d_in[5];
    const float* bl2 = (const float*)d_in[6];
    const float* Wr2 = (const float*)d_in[7];
    const float* Wl3 = (const float*)d_in[8];
    const float* bl3 = (const float*)d_in[9];
    const float* Wr3 = (const float*)d_in[10];
    const float* pw1 = (const float*)d_in[11];
    const float* pw2 = (const float*)d_in[12];
    const float* pw3 = (const float*)d_in[13];
    const float* W1  = (const float*)d_in[14];
    const float* b1  = (const float*)d_in[15];
    const float* W2  = (const float*)d_in[16];
    const float* b2  = (const float*)d_in[17];
    const float* W3  = (const float*)d_in[18];
    const float* b3  = (const float*)d_in[19];
    float* out = (float*)d_out;

    // workspace layout
    char* ws = (char*)d_ws;
    size_t off = 0;
    auto alloc = [&](size_t bytes) {
        char* p = ws + off;
        off = (off + bytes + 255) & ~(size_t)255;
        return p;
    };
    float* mean  = (float*)alloc((size_t)NN * FD * 4);
    float* hout  = (float*)alloc((size_t)NN * FD * 4);
    float* xp    = (float*)alloc((size_t)BG * K1 * FD * 4);
    float* sc    = (float*)alloc((size_t)NN * 4);
    int*   srcb  = (int*)  alloc((size_t)EE * 4);
    int*   dstb  = (int*)  alloc((size_t)EE * 4);
    float* emb   = (float*)alloc((size_t)EE * 4);
    int*   deg   = (int*)  alloc((size_t)NN * 4);
    int*   colb  = (int*)  alloc((size_t)NN * CAP * 4);   // 12.8 MB
    float* z     = (float*)alloc((size_t)BG * 256 * 4);

    // ================= layer 1 =================
    fill_first_kernel<<<BG, 1024, 0, stream>>>(ei, deg, colb);
    {
        int nb = (NN * 32 + 255) / 256;
        gather_agg_kernel<<<nb, 256, 0, stream>>>(deg, colb, x, mean, NN, nb);
    }
    {
        int nb = (NN + 63) / 64;
        sage_gemm_kernel<64><<<nb, 256, 0, stream>>>(mean, x, Wl1, Wr1, bl1, pw1, hout, sc, NN, nb);
    }
    topk_tail_kernel<<<BG, 1024, 0, stream>>>(sc, hout, NPG, K1, 512, xp,
                                              ei, ei + EE, (const float*)0,
                                              srcb, dstb, emb, deg, colb,
                                              z, 0, W1, b1, W2, b2, W3, b3, out);

    // ================= layer 2 =================
    const int N2 = BG * K1;   // 25000
    {
        int nb = (N2 * 32 + 255) / 256;
        gather_agg_kernel<<<nb, 256, 0, stream>>>(deg, colb, xp, mean, N2, nb);
    }
    {
        int nb = (N2 + 31) / 32;   // 782 blocks = 3.05/CU (was 391 = 1.53/CU)
        sage_gemm_kernel<32><<<nb, 256, 0, stream>>>(mean, xp, Wl2, Wr2, bl2, pw2, hout, sc, N2, nb);
    }
    topk_tail_kernel<<<BG, 1024, 0, stream>>>(sc, hout, K1, K2, 256, xp,
                                              srcb, dstb, emb,
                                              (int*)0, (int*)0, (float*)0, deg, colb,
                                              z, 1, W1, b1, W2, b2, W3, b3, out);

    // ================= layer 3 =================
    const int N3 = BG * K2;   // 12500
    {
        int nb = (N3 * 32 + 255) / 256;
        gather_agg_kernel<<<nb, 256, 0, stream>>>(deg, colb, xp, mean, N3, nb);
    }
    {
        int nb = (N3 + 31) / 32;   // 391 blocks (was 196 = 0.77/CU)
        sage_gemm_kernel<32><<<nb, 256, 0, stream>>>(mean, xp, Wl3, Wr3, bl3, pw3, hout, sc, N3, nb);
    }
    topk_tail_kernel<<<BG, 1024, 0, stream>>>(sc, hout, K2, K3, 128, xp,
                                              (const int*)0, (const int*)0, (const float*)0,
                                              (int*)0, (int*)0, (float*)0, (int*)0, (int*)0,
                                              z, 2, W1, b1, W2, b2, W3, b3, out);
}

// Round 14
// 269.883 us; speedup vs baseline: 1.2080x; 1.2080x over previous
//
#include <hip/hip_runtime.h>
#include <math.h>

// Problem constants (from reference)
#define BG    100        // graphs
#define NPG   500        // nodes per graph (layer 1)
#define FD    128        // feature dim (F_IN == H == 128)
#define EE    600000     // edges
#define EPG   6000       // edges per graph (contiguous, never cross graphs)
#define NN    50000      // total nodes layer 1
#define K1    250
#define K2    125
#define K3    63
#define CAP   64         // max in-degree capacity

typedef short v8s __attribute__((ext_vector_type(8)));
typedef float v4f __attribute__((ext_vector_type(4)));

// XCD-aligned swizzle (R9 win)
__device__ __forceinline__ int swz(int p, int N) {
    int j = p & 7, i = p >> 3;
    int chunk = N >> 3, rem = N & 7;
    int mj = j < rem ? j : rem;
    return j * chunk + mj + i;
}

// float -> bf16 RNE bits
__device__ __forceinline__ unsigned short f2bf(float f) {
    unsigned int u = __float_as_uint(f);
    unsigned int r = (u + 0x7FFFu + ((u >> 16) & 1u)) >> 16;
    return (unsigned short)r;
}
__device__ __forceinline__ float bf2f(unsigned short b) {
    return __uint_as_float(((unsigned int)b) << 16);
}

// ---------------- W prep: Wt_hi/Wt_lo[n][k] bf16, k = [Wl rows | Wr rows] ----------------
// One launch handles all 3 layers. Reads coalesced over n; writes scattered (small).
__global__ void prep_w_kernel(const float* __restrict__ Wl1, const float* __restrict__ Wr1,
                              const float* __restrict__ Wl2, const float* __restrict__ Wr2,
                              const float* __restrict__ Wl3, const float* __restrict__ Wr3,
                              unsigned short* __restrict__ wt_hi, unsigned short* __restrict__ wt_lo) {
    int id = blockIdx.x * blockDim.x + threadIdx.x;      // 3*256*128
    if (id >= 3 * 256 * 128) return;
    int layer = id >> 15, rem = id & 32767;
    int k = rem >> 7, n = rem & 127;
    const float* Wl = layer == 0 ? Wl1 : (layer == 1 ? Wl2 : Wl3);
    const float* Wr = layer == 0 ? Wr1 : (layer == 1 ? Wr2 : Wr3);
    float w = (k < 128) ? Wl[k * 128 + n] : Wr[(k - 128) * 128 + n];
    unsigned short hi = f2bf(w);
    unsigned short lo = f2bf(w - bf2f(hi));
    long long o = (long long)layer * 32768 + n * 256 + k;
    wt_hi[o] = hi;
    wt_lo[o] = lo;
}

// ---------------- layer-1 CSR build: one block per graph, LDS counters ----------------
__global__ __launch_bounds__(1024) void fill_first_kernel(const int* __restrict__ ei,
                                                          int* __restrict__ deg,
                                                          int* __restrict__ col) {
    __shared__ int lcnt[NPG];
    int b = swz(blockIdx.x, BG), tid = threadIdx.x;
    for (int i = tid; i < NPG; i += 1024) lcnt[i] = 0;
    __syncthreads();
    for (int e0 = tid; e0 < EPG; e0 += 1024) {
        int e = b * EPG + e0;
        int d = ei[EE + e];
        int pos = atomicAdd(&lcnt[d - b * NPG], 1);
        if (pos < CAP) col[(long long)d * CAP + pos] = ei[e];
    }
    __syncthreads();
    for (int i = tid; i < NPG; i += 1024) deg[b * NPG + i] = lcnt[i];
}

// ---------------- gather-aggregate (R12 form: 4-way pipelined) ----------------
__global__ void gather_agg_kernel(const int* __restrict__ deg, const int* __restrict__ col,
                                  const float* __restrict__ x, float* __restrict__ mean,
                                  int n, int NB) {
    int g = swz(blockIdx.x, NB) * 256 + threadIdx.x;
    int node = g >> 5, sub = g & 31;
    if (node >= n) return;
    int d = deg[node]; if (d > CAP) d = CAP;
    const int* cp = col + (long long)node * CAP;
    float ax = 0.0f, ay = 0.0f, az = 0.0f, aw = 0.0f;
    int j = 0;
    for (; j + 4 <= d; j += 4) {
        int s0 = cp[j], s1 = cp[j + 1], s2 = cp[j + 2], s3 = cp[j + 3];
        float4 v0 = ((const float4*)(x + (long long)s0 * FD))[sub];
        float4 v1 = ((const float4*)(x + (long long)s1 * FD))[sub];
        float4 v2 = ((const float4*)(x + (long long)s2 * FD))[sub];
        float4 v3 = ((const float4*)(x + (long long)s3 * FD))[sub];
        ax += v0.x; ay += v0.y; az += v0.z; aw += v0.w;
        ax += v1.x; ay += v1.y; az += v1.z; aw += v1.w;
        ax += v2.x; ay += v2.y; az += v2.z; aw += v2.w;
        ax += v3.x; ay += v3.y; az += v3.z; aw += v3.w;
    }
    for (; j < d; ++j) {
        float4 v = ((const float4*)(x + (long long)cp[j] * FD))[sub];
        ax += v.x; ay += v.y; az += v.z; aw += v.w;
    }
    float inv = 1.0f / fmaxf((float)d, 1.0f);
    float4 o; o.x = ax * inv; o.y = ay * inv; o.z = az * inv; o.w = aw * inv;
    ((float4*)(mean + (long long)node * FD))[sub] = o;
}

// ---------------- SAGE GEMM via bf16x2-split MFMA + score epilogue ----------------
// h = relu([mean|x]@[Wl;Wr] + bl), score = tanh(h.pw/||pw||).
// 64 rows x 128 cols, 256 threads (4 waves x 16-row stripe of 8 16x16 tiles).
// Split: A=Ah+Al, W=Wh+Wl_; acc += Al*Wh + Ah*Wl_ + Ah*Wh (rel err ~2^-18,
// protects jax.lax.top_k ordering; plain bf16 would flip selections).
// Frag layouts (guide-verified): A[m=lane&15][k=quad*8+j]; B[n=lane&15][k=quad*8+j];
// C/D col=lane&15, row=quad*4+reg (m89).
__global__ __launch_bounds__(256) void sage_gemm_mfma_kernel(
        const float* __restrict__ mean, const float* __restrict__ x,
        const unsigned short* __restrict__ wt_hi, const unsigned short* __restrict__ wt_lo,
        const float* __restrict__ bl, const float* __restrict__ pw,
        float* __restrict__ hout, float* __restrict__ score, int M, int NB) {
    __shared__ unsigned short Ah[64 * 40], Al[64 * 40];     // [row][k] bf16, stride 40
    __shared__ unsigned short Bh[128 * 40], Bl[128 * 40];   // [n][k] bf16, stride 40
    __shared__ float spart[64 * 16];
    __shared__ float snrmp[16];
    int tid  = threadIdx.x;
    int wave = tid >> 6, lane = tid & 63;
    int quad = lane >> 4, l15 = lane & 15;
    int row0 = swz(blockIdx.x, NB) * 64;

    v4f acc[8];
#pragma unroll
    for (int t = 0; t < 8; t++) acc[t] = (v4f){0.f, 0.f, 0.f, 0.f};

    if (tid < 16) {
        float s = 0.f;
#pragma unroll
        for (int t = 0; t < 8; t++) { float p = pw[t * 16 + tid]; s += p * p; }
        snrmp[tid] = s;
    }

    int arow = tid >> 2;            // 0..63
    int ak   = (tid & 3) * 8;       // 0,8,16,24
    int growA = row0 + arow; if (growA > M - 1) growA = M - 1;
    int brow = tid >> 1;            // 0..127 (n)
    int bk   = (tid & 1) * 16;      // 0,16

    for (int kt = 0; kt < 8; ++kt) {
        // ---- stage A (convert fp32 -> bf16 hi/lo) ----
        {
            const float* Ab = (kt < 4) ? mean : x;
            const float* ap = Ab + (long long)growA * FD + ((kt < 4) ? kt : kt - 4) * 32 + ak;
            float4 v0 = *(const float4*)(ap);
            float4 v1 = *(const float4*)(ap + 4);
            float f[8] = {v0.x, v0.y, v0.z, v0.w, v1.x, v1.y, v1.z, v1.w};
            ushort4 h0, h1, l0, l1;
            unsigned short hb[8], lb[8];
#pragma unroll
            for (int q = 0; q < 8; q++) {
                hb[q] = f2bf(f[q]);
                lb[q] = f2bf(f[q] - bf2f(hb[q]));
            }
            h0 = make_ushort4(hb[0], hb[1], hb[2], hb[3]);
            h1 = make_ushort4(hb[4], hb[5], hb[6], hb[7]);
            l0 = make_ushort4(lb[0], lb[1], lb[2], lb[3]);
            l1 = make_ushort4(lb[4], lb[5], lb[6], lb[7]);
            *(ushort4*)&Ah[arow * 40 + ak]     = h0;
            *(ushort4*)&Ah[arow * 40 + ak + 4] = h1;
            *(ushort4*)&Al[arow * 40 + ak]     = l0;
            *(ushort4*)&Al[arow * 40 + ak + 4] = l1;
        }
        // ---- stage B (copy pre-converted Wt) ----
        {
            int klog = kt * 32;
            const uint4* sh = (const uint4*)(wt_hi + (long long)brow * 256 + klog + bk);
            const uint4* sl = (const uint4*)(wt_lo + (long long)brow * 256 + klog + bk);
            uint4 vh0 = sh[0], vh1 = sh[1];
            uint4 vl0 = sl[0], vl1 = sl[1];
            *(uint4*)&Bh[brow * 40 + bk]     = vh0;
            *(uint4*)&Bh[brow * 40 + bk + 8] = vh1;
            *(uint4*)&Bl[brow * 40 + bk]     = vl0;
            *(uint4*)&Bl[brow * 40 + bk + 8] = vl1;
        }
        __syncthreads();
        // ---- MFMA ----
        v8s a_h = *(const v8s*)&Ah[(16 * wave + l15) * 40 + quad * 8];
        v8s a_l = *(const v8s*)&Al[(16 * wave + l15) * 40 + quad * 8];
#pragma unroll
        for (int t = 0; t < 8; t++) {
            v8s b_h = *(const v8s*)&Bh[(t * 16 + l15) * 40 + quad * 8];
            v8s b_l = *(const v8s*)&Bl[(t * 16 + l15) * 40 + quad * 8];
            acc[t] = __builtin_amdgcn_mfma_f32_16x16x32_bf16(a_l, b_h, acc[t], 0, 0, 0);
            acc[t] = __builtin_amdgcn_mfma_f32_16x16x32_bf16(a_h, b_l, acc[t], 0, 0, 0);
            acc[t] = __builtin_amdgcn_mfma_f32_16x16x32_bf16(a_h, b_h, acc[t], 0, 0, 0);
        }
        __syncthreads();
    }

    // ---- epilogue: bias + relu + store h + score partials ----
    int rbase = row0 + 16 * wave + quad * 4;
    float part[4] = {0.f, 0.f, 0.f, 0.f};
#pragma unroll
    for (int t = 0; t < 8; t++) {
        int colc = t * 16 + l15;
        float blv = bl[colc];
        float pwv = pw[colc];
#pragma unroll
        for (int reg = 0; reg < 4; reg++) {
            float h = fmaxf(acc[t][reg] + blv, 0.0f);
            part[reg] += h * pwv;
            int grow = rbase + reg;
            if (grow < M) hout[(long long)grow * FD + colc] = h;
        }
    }
#pragma unroll
    for (int reg = 0; reg < 4; reg++)
        spart[(16 * wave + quad * 4 + reg) * 16 + l15] = part[reg];
    __syncthreads();
    if (tid < 64) {
        int grow = row0 + tid;
        if (grow < M) {
            float dot = 0.0f;
#pragma unroll
            for (int i = 0; i < 16; i++) dot += spart[tid * 16 + i];
            float nr = 0.0f;
#pragma unroll
            for (int i = 0; i < 16; i++) nr += snrmp[i];
            score[grow] = tanhf(dot / sqrtf(nr));
        }
    }
}

// ---------------- fused per-graph tail (R12 form) ----------------
__global__ __launch_bounds__(1024) void topk_tail_kernel(
        const float* __restrict__ score, const float* __restrict__ hout,
        int n_per, int k, int SN,
        float* __restrict__ xp,
        const int* __restrict__ esrc, const int* __restrict__ edst,
        const float* __restrict__ em_in,
        int* __restrict__ src_out, int* __restrict__ dst_out, float* __restrict__ em_out,
        int* __restrict__ next_deg, int* __restrict__ next_col,
        float* __restrict__ z, int mode,
        const float* __restrict__ W1, const float* __restrict__ b1,
        const float* __restrict__ W2, const float* __restrict__ b2,
        const float* __restrict__ W3, const float* __restrict__ b3,
        float* __restrict__ out) {
    __shared__ float skey[512];
    __shared__ int   sidx[512];
    __shared__ int   lmap[512];
    __shared__ int   lcnt[512];
    __shared__ float pmax[1024];
    __shared__ float psum[1024];
    __shared__ float zs[256], t1[128], t2[64], t3[16];
    int b = swz(blockIdx.x, BG), tid = threadIdx.x;

    for (int i = tid; i < SN; i += 1024) {
        if (i < n_per) { skey[i] = score[b * n_per + i]; sidx[i] = i; }
        else           { skey[i] = -INFINITY;            sidx[i] = 0x7fffffff; }
        lmap[i] = -1;
        lcnt[i] = 0;
    }
    __syncthreads();

    for (int ks = 2; ks <= SN; ks <<= 1) {
        for (int j = ks >> 1; j > 0; j >>= 1) {
            for (int i = tid; i < SN; i += 1024) {
                int l = i ^ j;
                if (l > i) {
                    float ki = skey[i], kl = skey[l];
                    int   ii = sidx[i], il = sidx[l];
                    bool before = (ki > kl) || (ki == kl && ii < il);
                    bool up = ((i & ks) == 0);
                    if (up ? !before : before) {
                        skey[i] = kl; skey[l] = ki;
                        sidx[i] = il; sidx[l] = ii;
                    }
                }
            }
            __syncthreads();
        }
    }

    for (int i = tid; i < k; i += 1024) lmap[sidx[i]] = i;
    __syncthreads();

    if (esrc) {
        int nbase = b * n_per, kbase = b * k;
        for (int e0 = tid; e0 < EPG; e0 += 1024) {
            int e = b * EPG + e0;
            bool alive = em_in ? (em_in[e] != 0.0f) : true;
            if (alive) {
                int ls = lmap[esrc[e] - nbase];
                int ld = lmap[edst[e] - nbase];
                bool keep = (ls >= 0) && (ld >= 0);
                if (keep) {
                    int pos = atomicAdd(&lcnt[ld], 1);
                    if (pos < CAP) next_col[(long long)(kbase + ld) * CAP + pos] = kbase + ls;
                }
                if (em_out) {
                    em_out[e]  = keep ? 1.0f : 0.0f;
                    src_out[e] = keep ? kbase + ls : 0;
                    dst_out[e] = keep ? kbase + ld : 0;
                }
            } else if (em_out) {
                em_out[e] = 0.0f; src_out[e] = 0; dst_out[e] = 0;
            }
        }
        __syncthreads();
        for (int i = tid; i < k; i += 1024) next_deg[b * k + i] = lcnt[i];
    }

    int c = tid & 127, s = tid >> 7;
    float mx = -INFINITY, sm = 0.0f;
    {
        int r = s;
        long long hbase = (long long)b * n_per * FD + c;
        long long xbase = (long long)b * k * FD + c;
        for (; r + 24 < k; r += 32) {
            int i0 = sidx[r], i1 = sidx[r + 8], i2 = sidx[r + 16], i3 = sidx[r + 24];
            float k0 = skey[r], k1 = skey[r + 8], k2 = skey[r + 16], k3 = skey[r + 24];
            float v0 = hout[hbase + (long long)i0 * FD] * k0;
            float v1 = hout[hbase + (long long)i1 * FD] * k1;
            float v2 = hout[hbase + (long long)i2 * FD] * k2;
            float v3 = hout[hbase + (long long)i3 * FD] * k3;
            xp[xbase + (long long)(r)      * FD] = v0;
            xp[xbase + (long long)(r + 8)  * FD] = v1;
            xp[xbase + (long long)(r + 16) * FD] = v2;
            xp[xbase + (long long)(r + 24) * FD] = v3;
            mx = fmaxf(mx, v0); sm += v0;
            mx = fmaxf(mx, v1); sm += v1;
            mx = fmaxf(mx, v2); sm += v2;
            mx = fmaxf(mx, v3); sm += v3;
        }
        for (; r < k; r += 8) {
            float v = hout[hbase + (long long)sidx[r] * FD] * skey[r];
            xp[xbase + (long long)r * FD] = v;
            mx = fmaxf(mx, v); sm += v;
        }
    }
    pmax[tid] = mx; psum[tid] = sm;
    __syncthreads();
    if (tid < 128) {
        float m = -INFINITY, su = 0.0f;
#pragma unroll
        for (int i = 0; i < 8; i++) {
            m = fmaxf(m, pmax[i * 128 + tid]);
            su += psum[i * 128 + tid];
        }
        float mean = su / (float)k;
        if (mode == 0)      { z[b * 256 + tid] = m;  z[b * 256 + 128 + tid] = mean;  }
        else if (mode == 1) { z[b * 256 + tid] += m; z[b * 256 + 128 + tid] += mean; }
        else {
            zs[tid]       = z[b * 256 + tid] + m;
            zs[128 + tid] = z[b * 256 + 128 + tid] + mean;
        }
    }
    if (mode == 2) {
        __syncthreads();
        if (tid < 128) {
            float a = b1[tid];
            for (int kk = 0; kk < 256; kk++) a += zs[kk] * W1[kk * 128 + tid];
            t1[tid] = fmaxf(a, 0.0f);
        }
        __syncthreads();
        if (tid < 64) {
            float a = b2[tid];
            for (int kk = 0; kk < 128; kk++) a += t1[kk] * W2[kk * 64 + tid];
            t2[tid] = fmaxf(a, 0.0f);
        }
        __syncthreads();
        if (tid < 10) {
            float a = b3[tid];
            for (int kk = 0; kk < 64; kk++) a += t2[kk] * W3[kk * 10 + tid];
            t3[tid] = a;
        }
        __syncthreads();
        if (tid == 0) {
            float m = -INFINITY;
            for (int i = 0; i < 10; i++) m = fmaxf(m, t3[i]);
            float su = 0.0f;
            for (int i = 0; i < 10; i++) su += expf(t3[i] - m);
            float ls = logf(su);
            for (int i = 0; i < 10; i++) out[b * 10 + i] = t3[i] - m - ls;
        }
    }
}

extern "C" void kernel_launch(void* const* d_in, const int* in_sizes, int n_in,
                              void* d_out, int out_size, void* d_ws, size_t ws_size,
                              hipStream_t stream) {
    (void)in_sizes; (void)n_in; (void)out_size; (void)ws_size;
    const float* x   = (const float*)d_in[0];
    const int*   ei  = (const int*)d_in[1];
    const float* Wl1 = (const float*)d_in[2];
    const float* bl1 = (const float*)d_in[3];
    const float* Wr1 = (const float*)d_in[4];
    const float* Wl2 = (const float*)d_in[5];
    const float* bl2 = (const float*)d_in[6];
    const float* Wr2 = (const float*)d_in[7];
    const float* Wl3 = (const float*)d_in[8];
    const float* bl3 = (const float*)d_in[9];
    const float* Wr3 = (const float*)d_in[10];
    const float* pw1 = (const float*)d_in[11];
    const float* pw2 = (const float*)d_in[12];
    const float* pw3 = (const float*)d_in[13];
    const float* W1  = (const float*)d_in[14];
    const float* b1  = (const float*)d_in[15];
    const float* W2  = (const float*)d_in[16];
    const float* b2  = (const float*)d_in[17];
    const float* W3  = (const float*)d_in[18];
    const float* b3  = (const float*)d_in[19];
    float* out = (float*)d_out;

    // workspace layout
    char* ws = (char*)d_ws;
    size_t off = 0;
    auto alloc = [&](size_t bytes) {
        char* p = ws + off;
        off = (off + bytes + 255) & ~(size_t)255;
        return p;
    };
    float* mean  = (float*)alloc((size_t)NN * FD * 4);
    float* hout  = (float*)alloc((size_t)NN * FD * 4);
    float* xp    = (float*)alloc((size_t)BG * K1 * FD * 4);
    float* sc    = (float*)alloc((size_t)NN * 4);
    int*   srcb  = (int*)  alloc((size_t)EE * 4);
    int*   dstb  = (int*)  alloc((size_t)EE * 4);
    float* emb   = (float*)alloc((size_t)EE * 4);
    int*   deg   = (int*)  alloc((size_t)NN * 4);
    int*   colb  = (int*)  alloc((size_t)NN * CAP * 4);   // 12.8 MB
    float* z     = (float*)alloc((size_t)BG * 256 * 4);
    unsigned short* wt_hi = (unsigned short*)alloc((size_t)3 * 32768 * 2);
    unsigned short* wt_lo = (unsigned short*)alloc((size_t)3 * 32768 * 2);

    // ================= prep =================
    prep_w_kernel<<<(3 * 32768 + 255) / 256, 256, 0, stream>>>(Wl1, Wr1, Wl2, Wr2, Wl3, Wr3,
                                                               wt_hi, wt_lo);
    fill_first_kernel<<<BG, 1024, 0, stream>>>(ei, deg, colb);

    // ================= layer 1 =================
    {
        int nb = (NN * 32 + 255) / 256;
        gather_agg_kernel<<<nb, 256, 0, stream>>>(deg, colb, x, mean, NN, nb);
    }
    {
        int nb = (NN + 63) / 64;
        sage_gemm_mfma_kernel<<<nb, 256, 0, stream>>>(mean, x, wt_hi, wt_lo,
                                                      bl1, pw1, hout, sc, NN, nb);
    }
    topk_tail_kernel<<<BG, 1024, 0, stream>>>(sc, hout, NPG, K1, 512, xp,
                                              ei, ei + EE, (const float*)0,
                                              srcb, dstb, emb, deg, colb,
                                              z, 0, W1, b1, W2, b2, W3, b3, out);

    // ================= layer 2 =================
    const int N2 = BG * K1;   // 25000
    {
        int nb = (N2 * 32 + 255) / 256;
        gather_agg_kernel<<<nb, 256, 0, stream>>>(deg, colb, xp, mean, N2, nb);
    }
    {
        int nb = (N2 + 63) / 64;
        sage_gemm_mfma_kernel<<<nb, 256, 0, stream>>>(mean, xp, wt_hi + 32768, wt_lo + 32768,
                                                      bl2, pw2, hout, sc, N2, nb);
    }
    topk_tail_kernel<<<BG, 1024, 0, stream>>>(sc, hout, K1, K2, 256, xp,
                                              srcb, dstb, emb,
                                              (int*)0, (int*)0, (float*)0, deg, colb,
                                              z, 1, W1, b1, W2, b2, W3, b3, out);

    // ================= layer 3 =================
    const int N3 = BG * K2;   // 12500
    {
        int nb = (N3 * 32 + 255) / 256;
        gather_agg_kernel<<<nb, 256, 0, stream>>>(deg, colb, xp, mean, N3, nb);
    }
    {
        int nb = (N3 + 63) / 64;
        sage_gemm_mfma_kernel<<<nb, 256, 0, stream>>>(mean, xp, wt_hi + 65536, wt_lo + 65536,
                                                      bl3, pw3, hout, sc, N3, nb);
    }
    topk_tail_kernel<<<BG, 1024, 0, stream>>>(sc, hout, K2, K3, 128, xp,
                                              (const int*)0, (const int*)0, (const float*)0,
                                              (int*)0, (int*)0, (float*)0, (int*)0, (int*)0,
                                              z, 2, W1, b1, W2, b2, W3, b3, out);
}

// Round 15
// 267.128 us; speedup vs baseline: 1.2205x; 1.0103x over previous
//
#include <hip/hip_runtime.h>
#include <math.h>

// Problem constants (from reference)
#define BG    100        // graphs
#define NPG   500        // nodes per graph (layer 1)
#define FD    128        // feature dim (F_IN == H == 128)
#define EE    600000     // edges
#define EPG   6000       // edges per graph (contiguous, never cross graphs)
#define NN    50000      // total nodes layer 1
#define K1    250
#define K2    125
#define K3    63
#define CAP   64         // max in-degree capacity

typedef short v8s __attribute__((ext_vector_type(8)));
typedef float v4f __attribute__((ext_vector_type(4)));

// XCD-aligned swizzle (R9 win)
__device__ __forceinline__ int swz(int p, int N) {
    int j = p & 7, i = p >> 3;
    int chunk = N >> 3, rem = N & 7;
    int mj = j < rem ? j : rem;
    return j * chunk + mj + i;
}

// float -> bf16 RNE bits
__device__ __forceinline__ unsigned short f2bf(float f) {
    unsigned int u = __float_as_uint(f);
    unsigned int r = (u + 0x7FFFu + ((u >> 16) & 1u)) >> 16;
    return (unsigned short)r;
}
__device__ __forceinline__ float bf2f(unsigned short b) {
    return __uint_as_float(((unsigned int)b) << 16);
}

// ---------------- merged prep: blocks [0,BG) build layer-1 CSR (LDS counters);
// blocks [BG, BG+96) convert W -> Wt_hi/Wt_lo[n][k] bf16 (k = [Wl rows | Wr rows]) ----
__global__ __launch_bounds__(1024) void prep_fill_kernel(
        const int* __restrict__ ei, int* __restrict__ deg, int* __restrict__ col,
        const float* __restrict__ Wl1, const float* __restrict__ Wr1,
        const float* __restrict__ Wl2, const float* __restrict__ Wr2,
        const float* __restrict__ Wl3, const float* __restrict__ Wr3,
        unsigned short* __restrict__ wt_hi, unsigned short* __restrict__ wt_lo) {
    __shared__ int lcnt[NPG];
    int tid = threadIdx.x;
    if (blockIdx.x < BG) {
        int b = swz(blockIdx.x, BG);
        for (int i = tid; i < NPG; i += 1024) lcnt[i] = 0;
        __syncthreads();
        for (int e0 = tid; e0 < EPG; e0 += 1024) {
            int e = b * EPG + e0;
            int d = ei[EE + e];
            int pos = atomicAdd(&lcnt[d - b * NPG], 1);
            if (pos < CAP) col[(long long)d * CAP + pos] = ei[e];
        }
        __syncthreads();
        for (int i = tid; i < NPG; i += 1024) deg[b * NPG + i] = lcnt[i];
    } else {
        int id = (blockIdx.x - BG) * 1024 + tid;          // 3*256*128 = 98304
        if (id >= 3 * 256 * 128) return;
        int layer = id >> 15, rem = id & 32767;
        int k = rem >> 7, n = rem & 127;
        const float* Wl = layer == 0 ? Wl1 : (layer == 1 ? Wl2 : Wl3);
        const float* Wr = layer == 0 ? Wr1 : (layer == 1 ? Wr2 : Wr3);
        float w = (k < 128) ? Wl[k * 128 + n] : Wr[(k - 128) * 128 + n];
        unsigned short hi = f2bf(w);
        unsigned short lo = f2bf(w - bf2f(hi));
        long long o = (long long)layer * 32768 + n * 256 + k;
        wt_hi[o] = hi;
        wt_lo[o] = lo;
    }
}

// ---------------- gather-aggregate (R12 form: 4-way pipelined) ----------------
__global__ void gather_agg_kernel(const int* __restrict__ deg, const int* __restrict__ col,
                                  const float* __restrict__ x, float* __restrict__ mean,
                                  int n, int NB) {
    int g = swz(blockIdx.x, NB) * 256 + threadIdx.x;
    int node = g >> 5, sub = g & 31;
    if (node >= n) return;
    int d = deg[node]; if (d > CAP) d = CAP;
    const int* cp = col + (long long)node * CAP;
    float ax = 0.0f, ay = 0.0f, az = 0.0f, aw = 0.0f;
    int j = 0;
    for (; j + 4 <= d; j += 4) {
        int s0 = cp[j], s1 = cp[j + 1], s2 = cp[j + 2], s3 = cp[j + 3];
        float4 v0 = ((const float4*)(x + (long long)s0 * FD))[sub];
        float4 v1 = ((const float4*)(x + (long long)s1 * FD))[sub];
        float4 v2 = ((const float4*)(x + (long long)s2 * FD))[sub];
        float4 v3 = ((const float4*)(x + (long long)s3 * FD))[sub];
        ax += v0.x; ay += v0.y; az += v0.z; aw += v0.w;
        ax += v1.x; ay += v1.y; az += v1.z; aw += v1.w;
        ax += v2.x; ay += v2.y; az += v2.z; aw += v2.w;
        ax += v3.x; ay += v3.y; az += v3.z; aw += v3.w;
    }
    for (; j < d; ++j) {
        float4 v = ((const float4*)(x + (long long)cp[j] * FD))[sub];
        ax += v.x; ay += v.y; az += v.z; aw += v.w;
    }
    float inv = 1.0f / fmaxf((float)d, 1.0f);
    float4 o; o.x = ax * inv; o.y = ay * inv; o.z = az * inv; o.w = aw * inv;
    ((float4*)(mean + (long long)node * FD))[sub] = o;
}

// ---------------- SAGE GEMM via bf16x2-split MFMA, A direct-from-global ----------------
// h = relu([mean|x]@[Wl;Wr] + bl), score = tanh(h.pw/||pw||).
// 64 rows x 128 cols, 256 threads (4 waves x 16-row stripe of 8 16x16 tiles).
// A fragment is k-contiguous (A[m=lane&15][k=quad*8+j], guide-verified) and mean/x
// are row-major -> each lane loads its 8 fp32 directly from global (4 quads cover a
// full 128B line per row) and converts to bf16 hi/lo in registers. Only B (pre-
// converted Wt) is staged in LDS (16 KB/kt). Removes the A LDS round trip that
// dominated R14's GEMM. Split product: acc += Al*Bh + Ah*Bl + Ah*Bh (rel err ~2^-18,
// protects jax.lax.top_k ordering).
__global__ __launch_bounds__(256) void sage_gemm_mfma_kernel(
        const float* __restrict__ mean, const float* __restrict__ x,
        const unsigned short* __restrict__ wt_hi, const unsigned short* __restrict__ wt_lo,
        const float* __restrict__ bl, const float* __restrict__ pw,
        float* __restrict__ hout, float* __restrict__ score, int M, int NB) {
    __shared__ unsigned short Bh[128 * 40], Bl[128 * 40];   // [n][k] bf16, stride 40
    __shared__ float spart[64 * 16];
    __shared__ float snrmp[16];
    int tid  = threadIdx.x;
    int wave = tid >> 6, lane = tid & 63;
    int quad = lane >> 4, l15 = lane & 15;
    int row0 = swz(blockIdx.x, NB) * 64;

    v4f acc[8];
#pragma unroll
    for (int t = 0; t < 8; t++) acc[t] = (v4f){0.f, 0.f, 0.f, 0.f};

    if (tid < 16) {
        float s = 0.f;
#pragma unroll
        for (int t = 0; t < 8; t++) { float p = pw[t * 16 + tid]; s += p * p; }
        snrmp[tid] = s;
    }

    int growA = row0 + 16 * wave + l15; if (growA > M - 1) growA = M - 1;
    int brow = tid >> 1;            // 0..127 (n)
    int bk   = (tid & 1) * 16;      // 0,16

    for (int kt = 0; kt < 8; ++kt) {
        // ---- A: direct global load of this lane's fragment (8 fp32, k-contiguous) ----
        const float* Ab = (kt < 4) ? mean : x;
        const float* ap = Ab + (long long)growA * FD + ((kt < 4) ? kt : kt - 4) * 32 + quad * 8;
        float4 v0 = *(const float4*)(ap);
        float4 v1 = *(const float4*)(ap + 4);
        // ---- stage B (copy pre-converted Wt) ----
        {
            int klog = kt * 32;
            const uint4* sh = (const uint4*)(wt_hi + (long long)brow * 256 + klog + bk);
            const uint4* sl = (const uint4*)(wt_lo + (long long)brow * 256 + klog + bk);
            uint4 vh0 = sh[0], vh1 = sh[1];
            uint4 vl0 = sl[0], vl1 = sl[1];
            *(uint4*)&Bh[brow * 40 + bk]     = vh0;
            *(uint4*)&Bh[brow * 40 + bk + 8] = vh1;
            *(uint4*)&Bl[brow * 40 + bk]     = vl0;
            *(uint4*)&Bl[brow * 40 + bk + 8] = vl1;
        }
        // ---- convert A to hi/lo in registers ----
        float f[8] = {v0.x, v0.y, v0.z, v0.w, v1.x, v1.y, v1.z, v1.w};
        v8s a_h, a_l;
#pragma unroll
        for (int q = 0; q < 8; q++) {
            unsigned short hb = f2bf(f[q]);
            a_h[q] = (short)hb;
            a_l[q] = (short)f2bf(f[q] - bf2f(hb));
        }
        __syncthreads();
        // ---- MFMA over the 8 column tiles ----
#pragma unroll
        for (int t = 0; t < 8; t++) {
            v8s b_h = *(const v8s*)&Bh[(t * 16 + l15) * 40 + quad * 8];
            v8s b_l = *(const v8s*)&Bl[(t * 16 + l15) * 40 + quad * 8];
            acc[t] = __builtin_amdgcn_mfma_f32_16x16x32_bf16(a_l, b_h, acc[t], 0, 0, 0);
            acc[t] = __builtin_amdgcn_mfma_f32_16x16x32_bf16(a_h, b_l, acc[t], 0, 0, 0);
            acc[t] = __builtin_amdgcn_mfma_f32_16x16x32_bf16(a_h, b_h, acc[t], 0, 0, 0);
        }
        __syncthreads();
    }

    // ---- epilogue: bias + relu + store h + score partials ----
    int rbase = row0 + 16 * wave + quad * 4;
    float part[4] = {0.f, 0.f, 0.f, 0.f};
#pragma unroll
    for (int t = 0; t < 8; t++) {
        int colc = t * 16 + l15;
        float blv = bl[colc];
        float pwv = pw[colc];
#pragma unroll
        for (int reg = 0; reg < 4; reg++) {
            float h = fmaxf(acc[t][reg] + blv, 0.0f);
            part[reg] += h * pwv;
            int grow = rbase + reg;
            if (grow < M) hout[(long long)grow * FD + colc] = h;
        }
    }
#pragma unroll
    for (int reg = 0; reg < 4; reg++)
        spart[(16 * wave + quad * 4 + reg) * 16 + l15] = part[reg];
    __syncthreads();
    if (tid < 64) {
        int grow = row0 + tid;
        if (grow < M) {
            float dot = 0.0f;
#pragma unroll
            for (int i = 0; i < 16; i++) dot += spart[tid * 16 + i];
            float nr = 0.0f;
#pragma unroll
            for (int i = 0; i < 16; i++) nr += snrmp[i];
            score[grow] = tanhf(dot / sqrtf(nr));
        }
    }
}

// ---------------- fused per-graph tail (R12 form) ----------------
__global__ __launch_bounds__(1024) void topk_tail_kernel(
        const float* __restrict__ score, const float* __restrict__ hout,
        int n_per, int k, int SN,
        float* __restrict__ xp,
        const int* __restrict__ esrc, const int* __restrict__ edst,
        const float* __restrict__ em_in,
        int* __restrict__ src_out, int* __restrict__ dst_out, float* __restrict__ em_out,
        int* __restrict__ next_deg, int* __restrict__ next_col,
        float* __restrict__ z, int mode,
        const float* __restrict__ W1, const float* __restrict__ b1,
        const float* __restrict__ W2, const float* __restrict__ b2,
        const float* __restrict__ W3, const float* __restrict__ b3,
        float* __restrict__ out) {
    __shared__ float skey[512];
    __shared__ int   sidx[512];
    __shared__ int   lmap[512];
    __shared__ int   lcnt[512];
    __shared__ float pmax[1024];
    __shared__ float psum[1024];
    __shared__ float zs[256], t1[128], t2[64], t3[16];
    int b = swz(blockIdx.x, BG), tid = threadIdx.x;

    for (int i = tid; i < SN; i += 1024) {
        if (i < n_per) { skey[i] = score[b * n_per + i]; sidx[i] = i; }
        else           { skey[i] = -INFINITY;            sidx[i] = 0x7fffffff; }
        lmap[i] = -1;
        lcnt[i] = 0;
    }
    __syncthreads();

    for (int ks = 2; ks <= SN; ks <<= 1) {
        for (int j = ks >> 1; j > 0; j >>= 1) {
            for (int i = tid; i < SN; i += 1024) {
                int l = i ^ j;
                if (l > i) {
                    float ki = skey[i], kl = skey[l];
                    int   ii = sidx[i], il = sidx[l];
                    bool before = (ki > kl) || (ki == kl && ii < il);
                    bool up = ((i & ks) == 0);
                    if (up ? !before : before) {
                        skey[i] = kl; skey[l] = ki;
                        sidx[i] = il; sidx[l] = ii;
                    }
                }
            }
            __syncthreads();
        }
    }

    for (int i = tid; i < k; i += 1024) lmap[sidx[i]] = i;
    __syncthreads();

    if (esrc) {
        int nbase = b * n_per, kbase = b * k;
        for (int e0 = tid; e0 < EPG; e0 += 1024) {
            int e = b * EPG + e0;
            bool alive = em_in ? (em_in[e] != 0.0f) : true;
            if (alive) {
                int ls = lmap[esrc[e] - nbase];
                int ld = lmap[edst[e] - nbase];
                bool keep = (ls >= 0) && (ld >= 0);
                if (keep) {
                    int pos = atomicAdd(&lcnt[ld], 1);
                    if (pos < CAP) next_col[(long long)(kbase + ld) * CAP + pos] = kbase + ls;
                }
                if (em_out) {
                    em_out[e]  = keep ? 1.0f : 0.0f;
                    src_out[e] = keep ? kbase + ls : 0;
                    dst_out[e] = keep ? kbase + ld : 0;
                }
            } else if (em_out) {
                em_out[e] = 0.0f; src_out[e] = 0; dst_out[e] = 0;
            }
        }
        __syncthreads();
        for (int i = tid; i < k; i += 1024) next_deg[b * k + i] = lcnt[i];
    }

    int c = tid & 127, s = tid >> 7;
    float mx = -INFINITY, sm = 0.0f;
    {
        int r = s;
        long long hbase = (long long)b * n_per * FD + c;
        long long xbase = (long long)b * k * FD + c;
        for (; r + 24 < k; r += 32) {
            int i0 = sidx[r], i1 = sidx[r + 8], i2 = sidx[r + 16], i3 = sidx[r + 24];
            float k0 = skey[r], k1 = skey[r + 8], k2 = skey[r + 16], k3 = skey[r + 24];
            float v0 = hout[hbase + (long long)i0 * FD] * k0;
            float v1 = hout[hbase + (long long)i1 * FD] * k1;
            float v2 = hout[hbase + (long long)i2 * FD] * k2;
            float v3 = hout[hbase + (long long)i3 * FD] * k3;
            xp[xbase + (long long)(r)      * FD] = v0;
            xp[xbase + (long long)(r + 8)  * FD] = v1;
            xp[xbase + (long long)(r + 16) * FD] = v2;
            xp[xbase + (long long)(r + 24) * FD] = v3;
            mx = fmaxf(mx, v0); sm += v0;
            mx = fmaxf(mx, v1); sm += v1;
            mx = fmaxf(mx, v2); sm += v2;
            mx = fmaxf(mx, v3); sm += v3;
        }
        for (; r < k; r += 8) {
            float v = hout[hbase + (long long)sidx[r] * FD] * skey[r];
            xp[xbase + (long long)r * FD] = v;
            mx = fmaxf(mx, v); sm += v;
        }
    }
    pmax[tid] = mx; psum[tid] = sm;
    __syncthreads();
    if (tid < 128) {
        float m = -INFINITY, su = 0.0f;
#pragma unroll
        for (int i = 0; i < 8; i++) {
            m = fmaxf(m, pmax[i * 128 + tid]);
            su += psum[i * 128 + tid];
        }
        float mean = su / (float)k;
        if (mode == 0)      { z[b * 256 + tid] = m;  z[b * 256 + 128 + tid] = mean;  }
        else if (mode == 1) { z[b * 256 + tid] += m; z[b * 256 + 128 + tid] += mean; }
        else {
            zs[tid]       = z[b * 256 + tid] + m;
            zs[128 + tid] = z[b * 256 + 128 + tid] + mean;
        }
    }
    if (mode == 2) {
        __syncthreads();
        if (tid < 128) {
            float a = b1[tid];
            for (int kk = 0; kk < 256; kk++) a += zs[kk] * W1[kk * 128 + tid];
            t1[tid] = fmaxf(a, 0.0f);
        }
        __syncthreads();
        if (tid < 64) {
            float a = b2[tid];
            for (int kk = 0; kk < 128; kk++) a += t1[kk] * W2[kk * 64 + tid];
            t2[tid] = fmaxf(a, 0.0f);
        }
        __syncthreads();
        if (tid < 10) {
            float a = b3[tid];
            for (int kk = 0; kk < 64; kk++) a += t2[kk] * W3[kk * 10 + tid];
            t3[tid] = a;
        }
        __syncthreads();
        if (tid == 0) {
            float m = -INFINITY;
            for (int i = 0; i < 10; i++) m = fmaxf(m, t3[i]);
            float su = 0.0f;
            for (int i = 0; i < 10; i++) su += expf(t3[i] - m);
            float ls = logf(su);
            for (int i = 0; i < 10; i++) out[b * 10 + i] = t3[i] - m - ls;
        }
    }
}

extern "C" void kernel_launch(void* const* d_in, const int* in_sizes, int n_in,
                              void* d_out, int out_size, void* d_ws, size_t ws_size,
                              hipStream_t stream) {
    (void)in_sizes; (void)n_in; (void)out_size; (void)ws_size;
    const float* x   = (const float*)d_in[0];
    const int*   ei  = (const int*)d_in[1];
    const float* Wl1 = (const float*)d_in[2];
    const float* bl1 = (const float*)d_in[3];
    const float* Wr1 = (const float*)d_in[4];
    const float* Wl2 = (const float*)d_in[5];
    const float* bl2 = (const float*)d_in[6];
    const float* Wr2 = (const float*)d_in[7];
    const float* Wl3 = (const float*)d_in[8];
    const float* bl3 = (const float*)d_in[9];
    const float* Wr3 = (const float*)d_in[10];
    const float* pw1 = (const float*)d_in[11];
    const float* pw2 = (const float*)d_in[12];
    const float* pw3 = (const float*)d_in[13];
    const float* W1  = (const float*)d_in[14];
    const float* b1  = (const float*)d_in[15];
    const float* W2  = (const float*)d_in[16];
    const float* b2  = (const float*)d_in[17];
    const float* W3  = (const float*)d_in[18];
    const float* b3  = (const float*)d_in[19];
    float* out = (float*)d_out;

    // workspace layout
    char* ws = (char*)d_ws;
    size_t off = 0;
    auto alloc = [&](size_t bytes) {
        char* p = ws + off;
        off = (off + bytes + 255) & ~(size_t)255;
        return p;
    };
    float* mean  = (float*)alloc((size_t)NN * FD * 4);
    float* hout  = (float*)alloc((size_t)NN * FD * 4);
    float* xp    = (float*)alloc((size_t)BG * K1 * FD * 4);
    float* sc    = (float*)alloc((size_t)NN * 4);
    int*   srcb  = (int*)  alloc((size_t)EE * 4);
    int*   dstb  = (int*)  alloc((size_t)EE * 4);
    float* emb   = (float*)alloc((size_t)EE * 4);
    int*   deg   = (int*)  alloc((size_t)NN * 4);
    int*   colb  = (int*)  alloc((size_t)NN * CAP * 4);   // 12.8 MB
    float* z     = (float*)alloc((size_t)BG * 256 * 4);
    unsigned short* wt_hi = (unsigned short*)alloc((size_t)3 * 32768 * 2);
    unsigned short* wt_lo = (unsigned short*)alloc((size_t)3 * 32768 * 2);

    // ================= prep (CSR build + W conversion, one launch) =================
    prep_fill_kernel<<<BG + 96, 1024, 0, stream>>>(ei, deg, colb,
                                                   Wl1, Wr1, Wl2, Wr2, Wl3, Wr3, wt_hi, wt_lo);

    // ================= layer 1 =================
    {
        int nb = (NN * 32 + 255) / 256;
        gather_agg_kernel<<<nb, 256, 0, stream>>>(deg, colb, x, mean, NN, nb);
    }
    {
        int nb = (NN + 63) / 64;
        sage_gemm_mfma_kernel<<<nb, 256, 0, stream>>>(mean, x, wt_hi, wt_lo,
                                                      bl1, pw1, hout, sc, NN, nb);
    }
    topk_tail_kernel<<<BG, 1024, 0, stream>>>(sc, hout, NPG, K1, 512, xp,
                                              ei, ei + EE, (const float*)0,
                                              srcb, dstb, emb, deg, colb,
                                              z, 0, W1, b1, W2, b2, W3, b3, out);

    // ================= layer 2 =================
    const int N2 = BG * K1;   // 25000
    {
        int nb = (N2 * 32 + 255) / 256;
        gather_agg_kernel<<<nb, 256, 0, stream>>>(deg, colb, xp, mean, N2, nb);
    }
    {
        int nb = (N2 + 63) / 64;
        sage_gemm_mfma_kernel<<<nb, 256, 0, stream>>>(mean, xp, wt_hi + 32768, wt_lo + 32768,
                                                      bl2, pw2, hout, sc, N2, nb);
    }
    topk_tail_kernel<<<BG, 1024, 0, stream>>>(sc, hout, K1, K2, 256, xp,
                                              srcb, dstb, emb,
                                              (int*)0, (int*)0, (float*)0, deg, colb,
                                              z, 1, W1, b1, W2, b2, W3, b3, out);

    // ================= layer 3 =================
    const int N3 = BG * K2;   // 12500
    {
        int nb = (N3 * 32 + 255) / 256;
        gather_agg_kernel<<<nb, 256, 0, stream>>>(deg, colb, xp, mean, N3, nb);
    }
    {
        int nb = (N3 + 63) / 64;
        sage_gemm_mfma_kernel<<<nb, 256, 0, stream>>>(mean, xp, wt_hi + 65536, wt_lo + 65536,
                                                      bl3, pw3, hout, sc, N3, nb);
    }
    topk_tail_kernel<<<BG, 1024, 0, stream>>>(sc, hout, K2, K3, 128, xp,
                                              (const int*)0, (const int*)0, (const float*)0,
                                              (int*)0, (int*)0, (float*)0, (int*)0, (int*)0,
                                              z, 2, W1, b1, W2, b2, W3, b3, out);
}